// Round 1
// baseline (1889.562 us; speedup 1.0000x reference)
//
#include <hip/hip_runtime.h>
#include <hip/hip_bf16.h>
#include <stdint.h>

#define E_ 4
#define T_ 4096
#define D_ 2048
#define H_ 8192

typedef __attribute__((ext_vector_type(8))) short bf16x8;
typedef __attribute__((ext_vector_type(4))) float f32x4;

// round-to-nearest-even f32 -> bf16 bit pattern
__device__ __forceinline__ unsigned short f2bf(float f) {
    unsigned int u = __float_as_uint(f);
    u = u + 0x7fffu + ((u >> 16) & 1u);
    return (unsigned short)(u >> 16);
}

// async global->LDS, 16B per lane. lds dest must be wave-uniform base; HW adds lane*16.
__device__ __forceinline__ void async16(const unsigned short* g, unsigned short* l) {
    auto gp = (const __attribute__((address_space(1))) unsigned int*)g;
    auto lp = (__attribute__((address_space(3))) unsigned int*)l;
    __builtin_amdgcn_global_load_lds(gp, lp, 16 /*bytes*/, 0 /*offset*/, 0 /*aux*/);
}

// ---------------- x: f32 -> bf16 (vectorized) ----------------
__global__ void cvt_x_kernel(const float4* __restrict__ in, uint2* __restrict__ out, long n4) {
    long i = (long)blockIdx.x * blockDim.x + threadIdx.x;
    long stride = (long)gridDim.x * blockDim.x;
    for (; i < n4; i += stride) {
        float4 v = in[i];
        uint2 o;
        o.x = (unsigned)f2bf(v.x) | ((unsigned)f2bf(v.y) << 16);
        o.y = (unsigned)f2bf(v.z) | ((unsigned)f2bf(v.w) << 16);
        out[i] = o;
    }
}

// ---------------- W (R x C, f32, row-major) -> Wt (C x R, bf16) per expert ----------------
// grid: (C/64, R/64, E), block 256
__global__ void transpose_cvt_kernel(const float* __restrict__ W, unsigned short* __restrict__ Wt,
                                     int R, int C) {
    __shared__ float tile[64][65];
    const float* Wp = W + (size_t)blockIdx.z * R * C;
    unsigned short* Wtp = Wt + (size_t)blockIdx.z * R * C;
    const int c0 = blockIdx.x * 64, r0 = blockIdx.y * 64;
    const int tc = threadIdx.x & 63;
    const int tr = threadIdx.x >> 6; // 0..3
#pragma unroll
    for (int i = 0; i < 16; ++i) {
        int r = tr * 16 + i;
        tile[r][tc] = Wp[(size_t)(r0 + r) * C + c0 + tc];
    }
    __syncthreads();
#pragma unroll
    for (int i = 0; i < 16; ++i) {
        int r = tr * 16 + i; // output row within transposed tile (= original col)
        Wtp[(size_t)(c0 + r) * R + r0 + tc] = f2bf(tile[tc][r]);
    }
}

// ---------------- GEMM: C[M][N] = A[M][K] * Bt[N][K]^T (+bias), bf16 inputs ----------------
// OUT_MODE 0: out = bf16(relu(acc + bias))   OUT_MODE 1: out = f32(acc + bias)
// 128x128 tile, 4 waves (2x2, each 64x64 = 4x4 frags of 16x16), BK=64, single-buffer LDS,
// global_load_lds width=16 staging (m97 structure).
template <int K, int OUT_MODE>
__global__ __launch_bounds__(256) void gemm_bt_kernel(
    const unsigned short* __restrict__ A,   // [E][M][K]
    const unsigned short* __restrict__ Bt,  // [E][N][K]
    const float* __restrict__ bias,         // [E][N]
    void* __restrict__ Cout,                // [E][M][N]
    int M, int N)
{
    constexpr int BM = 128, BN = 128, BK = 64;
    __shared__ __align__(16) unsigned short As[BM][BK];
    __shared__ __align__(16) unsigned short Bs[BN][BK];

    const int e = blockIdx.z;
    const unsigned short* Ae = A + (size_t)e * M * K;
    const unsigned short* Be = Bt + (size_t)e * N * K;
    const int bm0 = blockIdx.y * BM;
    const int bn0 = blockIdx.x * BN;
    const int tid = threadIdx.x;
    const int lane = tid & 63;
    const int wid = tid >> 6;
    const int wr = wid >> 1, wc = wid & 1;

    f32x4 acc[4][4] = {};

    // staging geometry: chunk cc = wid*4+i covers tile rows [cc*8, cc*8+8), lane covers
    // row cc*8 + lane/8, k-bytes (lane&7)*16  (LDS write is linear: base + lane*16)
    const int sk = (lane & 7) * 8;          // k element offset within BK
    const int srl = (lane >> 3);            // row within 8-row chunk

    for (int k0 = 0; k0 < K; k0 += BK) {
        __syncthreads(); // previous compute done before overwriting LDS
#pragma unroll
        for (int i = 0; i < 4; ++i) {
            const int row = wid * 32 + i * 8 + srl;
            async16(Ae + (size_t)(bm0 + row) * K + k0 + sk, &As[0][0] + (wid * 4 + i) * 512);
        }
#pragma unroll
        for (int i = 0; i < 4; ++i) {
            const int row = wid * 32 + i * 8 + srl;
            async16(Be + (size_t)(bn0 + row) * K + k0 + sk, &Bs[0][0] + (wid * 4 + i) * 512);
        }
        __syncthreads(); // staged data visible (compiler drains vmcnt before barrier)

#pragma unroll
        for (int kk = 0; kk < 2; ++kk) {
            bf16x8 af[4], bfr[4];
#pragma unroll
            for (int m = 0; m < 4; ++m)
                af[m] = *(const bf16x8*)&As[wr * 64 + m * 16 + (lane & 15)][kk * 32 + (lane >> 4) * 8];
#pragma unroll
            for (int n = 0; n < 4; ++n)
                bfr[n] = *(const bf16x8*)&Bs[wc * 64 + n * 16 + (lane & 15)][kk * 32 + (lane >> 4) * 8];
#pragma unroll
            for (int m = 0; m < 4; ++m)
#pragma unroll
                for (int n = 0; n < 4; ++n)
                    acc[m][n] = __builtin_amdgcn_mfma_f32_16x16x32_bf16(af[m], bfr[n], acc[m][n], 0, 0, 0);
        }
    }

    // epilogue: C/D layout col = lane&15, row = (lane>>4)*4 + j  [m89-verified]
    const int col = lane & 15;
    const int rowb = (lane >> 4) * 4;
    const float* bp = bias + (size_t)e * N;

    if (OUT_MODE == 0) {
        unsigned short* Y = (unsigned short*)Cout + (size_t)e * M * N;
#pragma unroll
        for (int n = 0; n < 4; ++n) {
            const int cg = bn0 + wc * 64 + n * 16 + col;
            const float b = bp[cg];
#pragma unroll
            for (int m = 0; m < 4; ++m) {
                const int rg0 = bm0 + wr * 64 + m * 16 + rowb;
#pragma unroll
                for (int j = 0; j < 4; ++j) {
                    float v = acc[m][n][j] + b;
                    v = fmaxf(v, 0.0f);
                    Y[(size_t)(rg0 + j) * N + cg] = f2bf(v);
                }
            }
        }
    } else {
        float* O = (float*)Cout + (size_t)e * M * N;
#pragma unroll
        for (int n = 0; n < 4; ++n) {
            const int cg = bn0 + wc * 64 + n * 16 + col;
            const float b = bp[cg];
#pragma unroll
            for (int m = 0; m < 4; ++m) {
                const int rg0 = bm0 + wr * 64 + m * 16 + rowb;
#pragma unroll
                for (int j = 0; j < 4; ++j) {
                    O[(size_t)(rg0 + j) * N + cg] = acc[m][n][j] + b;
                }
            }
        }
    }
}

extern "C" void kernel_launch(void* const* d_in, const int* in_sizes, int n_in,
                              void* d_out, int out_size, void* d_ws, size_t ws_size,
                              hipStream_t stream) {
    const float* x     = (const float*)d_in[0]; // (E,T,D)
    const float* fc1_w = (const float*)d_in[1]; // (E,D,H)
    const float* fc1_b = (const float*)d_in[2]; // (E,1,H)
    const float* fc2_w = (const float*)d_in[3]; // (E,H,D)
    const float* fc2_b = (const float*)d_in[4]; // (E,1,D)
    float* out = (float*)d_out;

    const size_t n_x  = (size_t)E_ * T_ * D_;  // 33.5M
    const size_t n_w1 = (size_t)E_ * D_ * H_;  // 67.1M
    const size_t n_w2 = (size_t)E_ * H_ * D_;  // 67.1M
    const size_t n_y1 = (size_t)E_ * T_ * H_;  // 134.2M

    const size_t need = (n_x + n_w1 + n_w2 + n_y1) * sizeof(unsigned short); // 604 MB
    if (ws_size < need) return; // workspace too small — will show as validation failure

    unsigned short* xb  = (unsigned short*)d_ws;
    unsigned short* w1t = xb + n_x;    // (E,H,D) = fc1_w transposed
    unsigned short* w2t = w1t + n_w1;  // (E,D,H) = fc2_w transposed
    unsigned short* y1  = w2t + n_w2;  // (E,T,H) post-ReLU intermediate

    // x -> bf16
    cvt_x_kernel<<<2048, 256, 0, stream>>>((const float4*)x, (uint2*)xb, (long)(n_x / 4));
    // fc1_w (E,D,H) -> w1t (E,H,D)
    {
        dim3 g(H_ / 64, D_ / 64, E_);
        transpose_cvt_kernel<<<g, 256, 0, stream>>>(fc1_w, w1t, D_, H_);
    }
    // fc2_w (E,H,D) -> w2t (E,D,H)
    {
        dim3 g(D_ / 64, H_ / 64, E_);
        transpose_cvt_kernel<<<g, 256, 0, stream>>>(fc2_w, w2t, H_, D_);
    }
    // GEMM1: y1 = relu(x @ W1 + b1), bf16 out
    {
        dim3 g(H_ / 128, T_ / 128, E_);
        gemm_bt_kernel<D_, 0><<<g, 256, 0, stream>>>(xb, w1t, fc1_b, (void*)y1, T_, H_);
    }
    // GEMM2: out = y1 @ W2 + b2, f32 out
    {
        dim3 g(D_ / 128, T_ / 128, E_);
        gemm_bt_kernel<H_, 1><<<g, 256, 0, stream>>>(y1, w2t, fc2_b, (void*)out, T_, D_);
    }
}

// Round 2
// 1224.120 us; speedup vs baseline: 1.5436x; 1.5436x over previous
//
#include <hip/hip_runtime.h>
#include <hip/hip_bf16.h>
#include <stdint.h>

#define E_ 4
#define T_ 4096
#define D_ 2048
#define H_ 8192

typedef __attribute__((ext_vector_type(8))) short bf16x8;
typedef __attribute__((ext_vector_type(4))) float f32x4;

// round-to-nearest-even f32 -> bf16 bit pattern
__device__ __forceinline__ unsigned short f2bf(float f) {
    unsigned int u = __float_as_uint(f);
    u = u + 0x7fffu + ((u >> 16) & 1u);
    return (unsigned short)(u >> 16);
}

// async global->LDS, 16B per lane. LDS dest is wave-uniform base; HW adds lane*16.
__device__ __forceinline__ void async16(const unsigned short* g, unsigned short* l) {
    auto gp = (const __attribute__((address_space(1))) unsigned int*)g;
    auto lp = (__attribute__((address_space(3))) unsigned int*)l;
    __builtin_amdgcn_global_load_lds(gp, lp, 16 /*bytes*/, 0 /*offset*/, 0 /*aux*/);
}

__device__ __forceinline__ f32x4 mfma16(bf16x8 a, bf16x8 b, f32x4 c) {
    return __builtin_amdgcn_mfma_f32_16x16x32_bf16(a, b, c, 0, 0, 0);
}

// ---------------- x: f32 -> bf16 (vectorized) ----------------
__global__ void cvt_x_kernel(const float4* __restrict__ in, uint2* __restrict__ out, long n4) {
    long i = (long)blockIdx.x * blockDim.x + threadIdx.x;
    long stride = (long)gridDim.x * blockDim.x;
    for (; i < n4; i += stride) {
        float4 v = in[i];
        uint2 o;
        o.x = (unsigned)f2bf(v.x) | ((unsigned)f2bf(v.y) << 16);
        o.y = (unsigned)f2bf(v.z) | ((unsigned)f2bf(v.w) << 16);
        out[i] = o;
    }
}

// ---------------- W (R x C, f32, row-major) -> Wt (C x R, bf16) per expert ----------------
__global__ void transpose_cvt_kernel(const float* __restrict__ W, unsigned short* __restrict__ Wt,
                                     int R, int C) {
    __shared__ float tile[64][65];
    const float* Wp = W + (size_t)blockIdx.z * R * C;
    unsigned short* Wtp = Wt + (size_t)blockIdx.z * R * C;
    const int c0 = blockIdx.x * 64, r0 = blockIdx.y * 64;
    const int tc = threadIdx.x & 63;
    const int tr = threadIdx.x >> 6; // 0..3
#pragma unroll
    for (int i = 0; i < 16; ++i) {
        int r = tr * 16 + i;
        tile[r][tc] = Wp[(size_t)(r0 + r) * C + c0 + tc];
    }
    __syncthreads();
#pragma unroll
    for (int i = 0; i < 16; ++i) {
        int r = tr * 16 + i;
        Wtp[(size_t)(c0 + r) * R + r0 + tc] = f2bf(tile[tc][r]);
    }
}

// ---------------- 256x256 8-phase GEMM: C[M][N] = A[M][K] * Bt[N][K]^T (+bias) ----------------
// 8 waves (2M x 4N), per-wave 128x64 output = acc[8][4] of 16x16 frags. BK=64.
// LDS: 2 dbuf x {A,B} x 2 halves x [128][64] bf16 = 128 KiB. XOR swizzle kel ^= (row&7)<<3
// applied on BOTH the pre-swizzled global_load_lds source and the ds_read address.
// Phase schedule per tile t (slot s=t&1), staging tile t+2 into slot s:
//   P1: ds_read B(all 4n x 2kk) + A-lo(4m x 2kk); bar; MFMA m0-3 x n0-1; lgkm drain; bar
//   P2: stage B0(t+2); bar; MFMA m0-3 x n2-3; bar
//   P3: ds_read A-hi; stage B1(t+2); bar; MFMA m4-7 x n0-1; lgkm drain; bar
//   P4: stage A0,A1(t+2); vmcnt(8|0); bar; MFMA m4-7 x n2-3; bar
// Region-death: B(slot s) dead after P1 drain, A after P3 drain -> stage targets are safe.
template <int K, int OUT_MODE>
__global__ __launch_bounds__(512, 2) void gemm256_kernel(
    const unsigned short* __restrict__ A,   // [E][M][K]
    const unsigned short* __restrict__ Bt,  // [E][N][K]
    const float* __restrict__ bias,         // [E][N]
    void* __restrict__ Cout,                // [E][M][N]
    int M, int N)
{
    constexpr int BK = 64;
    constexpr int NT = K / BK;
    __shared__ __align__(16) unsigned short L[2][2][2][128][64]; // [dbuf][A/B][half][row][kel]

    // ---- XCD-aware swizzle of the full linearized grid (nwg % 8 == 0 for all our grids)
    const int nx = gridDim.x, ny = gridDim.y;
    const int nwg = nx * ny * gridDim.z;
    const int w = (blockIdx.z * ny + blockIdx.y) * nx + blockIdx.x;
    const int cpx = nwg >> 3;
    const int lid = (w & 7) * cpx + (w >> 3);
    const int e  = lid / (nx * ny);
    const int r2 = lid % (nx * ny);
    const int by = r2 / nx, bx = r2 % nx;

    const unsigned short* Ae = A + (size_t)e * M * K;
    const unsigned short* Be = Bt + (size_t)e * N * K;
    const int bm0 = by * 256;
    const int bn0 = bx * 256;

    const int tid = threadIdx.x;
    const int lane = tid & 63;
    const int wid = tid >> 6;     // 0..7
    const int wr = wid >> 2;      // 0..1 (M half)
    const int wc = wid & 3;       // 0..3 (N quarter)

    // staging geometry (per wave, per call i in 0..1): rows wid*16 + i*8 + (lane>>3)
    const int srow = wid * 16 + (lane >> 3);
    const int skel = 8 * ((lane & 7) ^ (lane >> 3)); // pre-swizzled global k offset

    // fragment-read geometry
    const int fr = lane & 15;
    const int kq = lane >> 4;          // 0..3
    const int ksw = (lane & 7) << 3;   // read-side swizzle (elements)
    const int bh = wc >> 1;            // B half this wave reads
    const int brb = (wc & 1) * 64;     // B row base within half

    f32x4 acc[8][4] = {};

    auto stageA = [&](int t, int h) {
        const int k0 = t * BK;
        const int s = t & 1;
#pragma unroll
        for (int i = 0; i < 2; ++i) {
            async16(Ae + (size_t)(bm0 + h * 128 + srow + i * 8) * K + k0 + skel,
                    &L[s][0][h][wid * 16 + i * 8][0]);
        }
    };
    auto stageB = [&](int t, int h) {
        const int k0 = t * BK;
        const int s = t & 1;
#pragma unroll
        for (int i = 0; i < 2; ++i) {
            async16(Be + (size_t)(bn0 + h * 128 + srow + i * 8) * K + k0 + skel,
                    &L[s][1][h][wid * 16 + i * 8][0]);
        }
    };

    // ---- prologue: stage tiles 0 and 1 (8 loads each)
    stageB(0, 0); stageB(0, 1); stageA(0, 0); stageA(0, 1);
    stageB(1, 0); stageB(1, 1); stageA(1, 0); stageA(1, 1);
    asm volatile("s_waitcnt vmcnt(8)" ::: "memory"); // tile 0 arrived
    __builtin_amdgcn_s_barrier();

    bf16x8 a[4][2], b[4][2];

    for (int t = 0; t < NT; ++t) {
        const int s = t & 1;

        // ================ P1 ================
#pragma unroll
        for (int n = 0; n < 4; ++n)
#pragma unroll
            for (int kk = 0; kk < 2; ++kk)
                b[n][kk] = *(const bf16x8*)&L[s][1][bh][brb + n * 16 + fr][(kk * 32 + kq * 8) ^ ksw];
#pragma unroll
        for (int m = 0; m < 4; ++m)
#pragma unroll
            for (int kk = 0; kk < 2; ++kk)
                a[m][kk] = *(const bf16x8*)&L[s][0][wr][m * 16 + fr][(kk * 32 + kq * 8) ^ ksw];
        __builtin_amdgcn_s_barrier();
        __builtin_amdgcn_s_setprio(1);
#pragma unroll
        for (int m = 0; m < 4; ++m)
#pragma unroll
            for (int n = 0; n < 2; ++n)
#pragma unroll
                for (int kk = 0; kk < 2; ++kk)
                    acc[m][n] = mfma16(a[m][kk], b[n][kk], acc[m][n]);
        __builtin_amdgcn_s_setprio(0);
        asm volatile("s_waitcnt lgkmcnt(0)" ::: "memory"); // all P1 ds_reads landed: B + A-lo regions now dead
        __builtin_amdgcn_s_barrier();

        // ================ P2 ================
        if (t + 2 < NT) stageB(t + 2, 0);
        __builtin_amdgcn_s_barrier();
        __builtin_amdgcn_s_setprio(1);
#pragma unroll
        for (int m = 0; m < 4; ++m)
#pragma unroll
            for (int n = 2; n < 4; ++n)
#pragma unroll
                for (int kk = 0; kk < 2; ++kk)
                    acc[m][n] = mfma16(a[m][kk], b[n][kk], acc[m][n]);
        __builtin_amdgcn_s_setprio(0);
        __builtin_amdgcn_s_barrier();

        // ================ P3 ================
#pragma unroll
        for (int m = 0; m < 4; ++m)
#pragma unroll
            for (int kk = 0; kk < 2; ++kk)
                a[m][kk] = *(const bf16x8*)&L[s][0][wr][(m + 4) * 16 + fr][(kk * 32 + kq * 8) ^ ksw];
        if (t + 2 < NT) stageB(t + 2, 1);
        __builtin_amdgcn_s_barrier();
        __builtin_amdgcn_s_setprio(1);
#pragma unroll
        for (int m = 0; m < 4; ++m)
#pragma unroll
            for (int n = 0; n < 2; ++n)
#pragma unroll
                for (int kk = 0; kk < 2; ++kk)
                    acc[m + 4][n] = mfma16(a[m][kk], b[n][kk], acc[m + 4][n]);
        __builtin_amdgcn_s_setprio(0);
        asm volatile("s_waitcnt lgkmcnt(0)" ::: "memory"); // A-hi reads landed: A region dead
        __builtin_amdgcn_s_barrier();

        // ================ P4 ================
        if (t + 2 < NT) {
            stageA(t + 2, 0); stageA(t + 2, 1);
            asm volatile("s_waitcnt vmcnt(8)" ::: "memory"); // tile t+1 fully arrived; t+2's 8 in flight
        } else {
            asm volatile("s_waitcnt vmcnt(0)" ::: "memory"); // tail: drain remaining
        }
        __builtin_amdgcn_s_barrier();
        __builtin_amdgcn_s_setprio(1);
#pragma unroll
        for (int m = 0; m < 4; ++m)
#pragma unroll
            for (int n = 2; n < 4; ++n)
#pragma unroll
                for (int kk = 0; kk < 2; ++kk)
                    acc[m + 4][n] = mfma16(a[m][kk], b[n][kk], acc[m + 4][n]);
        __builtin_amdgcn_s_setprio(0);
        __builtin_amdgcn_s_barrier();
    }

    // ---- epilogue: C/D layout col = lane&15, row = (lane>>4)*4 + j
    const int rowq = (lane >> 4) * 4;
    const float* bp = bias + (size_t)e * N;

    if (OUT_MODE == 0) {
        unsigned short* Y = (unsigned short*)Cout + (size_t)e * M * N;
#pragma unroll
        for (int n = 0; n < 4; ++n) {
            const int cg = bn0 + wc * 64 + n * 16 + fr;
            const float bb = bp[cg];
#pragma unroll
            for (int m = 0; m < 8; ++m) {
                const int rg0 = bm0 + wr * 128 + m * 16 + rowq;
#pragma unroll
                for (int j = 0; j < 4; ++j) {
                    float v = acc[m][n][j] + bb;
                    v = fmaxf(v, 0.0f);
                    Y[(size_t)(rg0 + j) * N + cg] = f2bf(v);
                }
            }
        }
    } else {
        float* O = (float*)Cout + (size_t)e * M * N;
#pragma unroll
        for (int n = 0; n < 4; ++n) {
            const int cg = bn0 + wc * 64 + n * 16 + fr;
            const float bb = bp[cg];
#pragma unroll
            for (int m = 0; m < 8; ++m) {
                const int rg0 = bm0 + wr * 128 + m * 16 + rowq;
#pragma unroll
                for (int j = 0; j < 4; ++j) {
                    O[(size_t)(rg0 + j) * N + cg] = acc[m][n][j] + bb;
                }
            }
        }
    }
}

extern "C" void kernel_launch(void* const* d_in, const int* in_sizes, int n_in,
                              void* d_out, int out_size, void* d_ws, size_t ws_size,
                              hipStream_t stream) {
    const float* x     = (const float*)d_in[0]; // (E,T,D)
    const float* fc1_w = (const float*)d_in[1]; // (E,D,H)
    const float* fc1_b = (const float*)d_in[2]; // (E,1,H)
    const float* fc2_w = (const float*)d_in[3]; // (E,H,D)
    const float* fc2_b = (const float*)d_in[4]; // (E,1,D)
    float* out = (float*)d_out;

    const size_t n_x  = (size_t)E_ * T_ * D_;
    const size_t n_w1 = (size_t)E_ * D_ * H_;
    const size_t n_w2 = (size_t)E_ * H_ * D_;
    const size_t n_y1 = (size_t)E_ * T_ * H_;

    const size_t need = (n_x + n_w1 + n_w2 + n_y1) * sizeof(unsigned short);
    if (ws_size < need) return;

    unsigned short* xb  = (unsigned short*)d_ws;
    unsigned short* w1t = xb + n_x;    // (E,H,D)
    unsigned short* w2t = w1t + n_w1;  // (E,D,H)
    unsigned short* y1  = w2t + n_w2;  // (E,T,H)

    cvt_x_kernel<<<2048, 256, 0, stream>>>((const float4*)x, (uint2*)xb, (long)(n_x / 4));
    {
        dim3 g(H_ / 64, D_ / 64, E_);
        transpose_cvt_kernel<<<g, 256, 0, stream>>>(fc1_w, w1t, D_, H_);
    }
    {
        dim3 g(D_ / 64, H_ / 64, E_);
        transpose_cvt_kernel<<<g, 256, 0, stream>>>(fc2_w, w2t, H_, D_);
    }
    // GEMM1: y1 = relu(x @ W1 + b1), bf16 out. M=T, N=H, K=D
    {
        dim3 g(H_ / 256, T_ / 256, E_);
        gemm256_kernel<D_, 0><<<g, 512, 0, stream>>>(xb, w1t, fc1_b, (void*)y1, T_, H_);
    }
    // GEMM2: out = y1 @ W2 + b2, f32 out. M=T, N=D, K=H
    {
        dim3 g(D_ / 256, T_ / 256, E_);
        gemm256_kernel<H_, 1><<<g, 512, 0, stream>>>(y1, w2t, fc2_b, (void*)out, T_, D_);
    }
}

// Round 3
// 1209.511 us; speedup vs baseline: 1.5623x; 1.0121x over previous
//
#include <hip/hip_runtime.h>
#include <hip/hip_bf16.h>
#include <stdint.h>

#define E_ 4
#define T_ 4096
#define D_ 2048
#define H_ 8192

typedef __attribute__((ext_vector_type(8))) short bf16x8;
typedef __attribute__((ext_vector_type(4))) float f32x4;

// round-to-nearest-even f32 -> bf16 bit pattern
__device__ __forceinline__ unsigned short f2bf(float f) {
    unsigned int u = __float_as_uint(f);
    u = u + 0x7fffu + ((u >> 16) & 1u);
    return (unsigned short)(u >> 16);
}

// async global->LDS, 16B per lane. LDS dest is wave-uniform base; HW adds lane*16.
__device__ __forceinline__ void async16(const unsigned short* g, unsigned short* l) {
    auto gp = (const __attribute__((address_space(1))) unsigned int*)g;
    auto lp = (__attribute__((address_space(3))) unsigned int*)l;
    __builtin_amdgcn_global_load_lds(gp, lp, 16 /*bytes*/, 0 /*offset*/, 0 /*aux*/);
}

__device__ __forceinline__ f32x4 mfma16(bf16x8 a, bf16x8 b, f32x4 c) {
    return __builtin_amdgcn_mfma_f32_16x16x32_bf16(a, b, c, 0, 0, 0);
}

// ---------------- x: f32 -> bf16 (vectorized) ----------------
__global__ void cvt_x_kernel(const float4* __restrict__ in, uint2* __restrict__ out, long n4) {
    long i = (long)blockIdx.x * blockDim.x + threadIdx.x;
    long stride = (long)gridDim.x * blockDim.x;
    for (; i < n4; i += stride) {
        float4 v = in[i];
        uint2 o;
        o.x = (unsigned)f2bf(v.x) | ((unsigned)f2bf(v.y) << 16);
        o.y = (unsigned)f2bf(v.z) | ((unsigned)f2bf(v.w) << 16);
        out[i] = o;
    }
}

// ---------------- W (R x C, f32, row-major) -> Wt (C x R, bf16) per expert ----------------
__global__ void transpose_cvt_kernel(const float* __restrict__ W, unsigned short* __restrict__ Wt,
                                     int R, int C) {
    __shared__ float tile[64][65];
    const float* Wp = W + (size_t)blockIdx.z * R * C;
    unsigned short* Wtp = Wt + (size_t)blockIdx.z * R * C;
    const int c0 = blockIdx.x * 64, r0 = blockIdx.y * 64;
    const int tc = threadIdx.x & 63;
    const int tr = threadIdx.x >> 6; // 0..3
#pragma unroll
    for (int i = 0; i < 16; ++i) {
        int r = tr * 16 + i;
        tile[r][tc] = Wp[(size_t)(r0 + r) * C + c0 + tc];
    }
    __syncthreads();
#pragma unroll
    for (int i = 0; i < 16; ++i) {
        int r = tr * 16 + i;
        Wtp[(size_t)(c0 + r) * R + r0 + tc] = f2bf(tile[tc][r]);
    }
}

// ---------------- 256x256 GEMM: C[M][N] = A[M][K] * Bt[N][K]^T (+bias) ----------------
// 8 waves (2M x 4N), per-wave 128x64 output = acc[8][4] of 16x16 frags. BK=64.
// LDS: 2 dbuf x {A,B} x 2 halves x [128][64] bf16 = 128 KiB. XOR swizzle kel ^= (row&7)<<3
// on both the pre-swizzled global_load_lds source and the ds_read address (conflict-free,
// verified SQ_LDS_BANK_CONFLICT = 0).
// Per-tile schedule (2 barriers, register-pipelined within the tile):
//   vmcnt(8) ; bar            -- tile t staged data visible (t+1's 8 loads still in flight)
//   ds_read b[4][2] + a-lo    -- 16 reads
//   MFMA Q1+Q2 (a-lo x b, 32) -- a-hi ds_reads (8, reusing a regs) land under this cluster
//   lgkmcnt(0) ; bar          -- all slot-s reads register-landed across all waves
//   stage tile t+2 (8 gloads) -- into now-dead slot; pinned before compute
//   MFMA Q3+Q4 (a-hi x b, 32) -- covers stage issue + HBM latency
template <int K, int OUT_MODE>
__global__ __launch_bounds__(512, 2) void gemm256_kernel(
    const unsigned short* __restrict__ A,   // [E][M][K]
    const unsigned short* __restrict__ Bt,  // [E][N][K]
    const float* __restrict__ bias,         // [E][N]
    void* __restrict__ Cout,                // [E][M][N]
    int M, int N)
{
    constexpr int BK = 64;
    constexpr int NT = K / BK;
    __shared__ __align__(16) unsigned short L[2][2][2][128][64]; // [dbuf][A/B][half][row][kel]

    // ---- XCD-aware swizzle of the full linearized grid (nwg % 8 == 0 for all our grids)
    const int nx = gridDim.x, ny = gridDim.y;
    const int nwg = nx * ny * gridDim.z;
    const int w = (blockIdx.z * ny + blockIdx.y) * nx + blockIdx.x;
    const int cpx = nwg >> 3;
    const int lid = (w & 7) * cpx + (w >> 3);
    const int e  = lid / (nx * ny);
    const int r2 = lid % (nx * ny);
    const int by = r2 / nx, bx = r2 % nx;

    const unsigned short* Ae = A + (size_t)e * M * K;
    const unsigned short* Be = Bt + (size_t)e * N * K;
    const int bm0 = by * 256;
    const int bn0 = bx * 256;

    const int tid = threadIdx.x;
    const int lane = tid & 63;
    const int wid = tid >> 6;     // 0..7
    const int wr = wid >> 2;      // 0..1 (M half)
    const int wc = wid & 3;       // 0..3 (N quarter)

    // staging geometry: per call i in 0..1, rows wid*16 + i*8 + (lane>>3)
    const int srow = wid * 16 + (lane >> 3);
    const int skel = 8 * ((lane & 7) ^ (lane >> 3)); // pre-swizzled global k offset

    // fragment-read geometry
    const int fr = lane & 15;
    const int kq = lane >> 4;          // 0..3
    const int ksw = (lane & 7) << 3;   // read-side swizzle (elements)
    const int bh = wc >> 1;            // B half this wave reads
    const int brb = (wc & 1) * 64;     // B row base within half

    f32x4 acc[8][4] = {};

    auto stageA = [&](int t, int h) {
        const int k0 = t * BK;
        const int s = t & 1;
#pragma unroll
        for (int i = 0; i < 2; ++i) {
            async16(Ae + (size_t)(bm0 + h * 128 + srow + i * 8) * K + k0 + skel,
                    &L[s][0][h][wid * 16 + i * 8][0]);
        }
    };
    auto stageB = [&](int t, int h) {
        const int k0 = t * BK;
        const int s = t & 1;
#pragma unroll
        for (int i = 0; i < 2; ++i) {
            async16(Be + (size_t)(bn0 + h * 128 + srow + i * 8) * K + k0 + skel,
                    &L[s][1][h][wid * 16 + i * 8][0]);
        }
    };

    // ---- prologue: stage tiles 0 and 1 (8 loads each; 16 in flight)
    stageB(0, 0); stageB(0, 1); stageA(0, 0); stageA(0, 1);
    stageB(1, 0); stageB(1, 1); stageA(1, 0); stageA(1, 1);

    bf16x8 a[4][2], b[4][2];

    for (int t = 0; t < NT; ++t) {
        const int s = t & 1;

        // ---- tile-t data visible to all waves
        if (t == NT - 1) {
            asm volatile("s_waitcnt vmcnt(0)" ::: "memory");
        } else {
            asm volatile("s_waitcnt vmcnt(8)" ::: "memory");
        }
        __builtin_amdgcn_s_barrier();

        // ---- fragment reads: b (8) + a-lo (8)
#pragma unroll
        for (int n = 0; n < 2; ++n)
#pragma unroll
            for (int kk = 0; kk < 2; ++kk)
                b[n][kk] = *(const bf16x8*)&L[s][1][bh][brb + n * 16 + fr][(kk * 32 + kq * 8) ^ ksw];
#pragma unroll
        for (int m = 0; m < 4; ++m)
#pragma unroll
            for (int kk = 0; kk < 2; ++kk)
                a[m][kk] = *(const bf16x8*)&L[s][0][wr][m * 16 + fr][(kk * 32 + kq * 8) ^ ksw];
#pragma unroll
        for (int n = 2; n < 4; ++n)
#pragma unroll
            for (int kk = 0; kk < 2; ++kk)
                b[n][kk] = *(const bf16x8*)&L[s][1][bh][brb + n * 16 + fr][(kk * 32 + kq * 8) ^ ksw];

        // ---- Q1+Q2: a-lo x all b (32 MFMA)
        __builtin_amdgcn_s_setprio(1);
#pragma unroll
        for (int m = 0; m < 4; ++m)
#pragma unroll
            for (int n = 0; n < 4; ++n)
#pragma unroll
                for (int kk = 0; kk < 2; ++kk)
                    acc[m][n] = mfma16(a[m][kk], b[n][kk], acc[m][n]);
        __builtin_amdgcn_s_setprio(0);

        // ---- a-hi reads (reuse a regs; WAR vs Q1/Q2 handled by compiler dep tracking)
#pragma unroll
        for (int m = 0; m < 4; ++m)
#pragma unroll
            for (int kk = 0; kk < 2; ++kk)
                a[m][kk] = *(const bf16x8*)&L[s][0][wr][(m + 4) * 16 + fr][(kk * 32 + kq * 8) ^ ksw];

        // ---- all slot-s reads landed in registers, across all waves -> slot dead
        asm volatile("s_waitcnt lgkmcnt(0)" ::: "memory");
        __builtin_amdgcn_s_barrier();

        // ---- stage tile t+2 into the dead slot (8 gloads), pinned before Q3/Q4
        if (t + 2 < NT) {
            stageB(t + 2, 0); stageB(t + 2, 1);
            stageA(t + 2, 0); stageA(t + 2, 1);
        }
        __builtin_amdgcn_sched_barrier(0);

        // ---- Q3+Q4: a-hi x all b (32 MFMA) — covers stage issue + HBM latency
        __builtin_amdgcn_s_setprio(1);
#pragma unroll
        for (int m = 0; m < 4; ++m)
#pragma unroll
            for (int n = 0; n < 4; ++n)
#pragma unroll
                for (int kk = 0; kk < 2; ++kk)
                    acc[m + 4][n] = mfma16(a[m][kk], b[n][kk], acc[m + 4][n]);
        __builtin_amdgcn_s_setprio(0);
    }

    // ---- epilogue: C/D layout col = lane&15, row = (lane>>4)*4 + j
    const int rowq = (lane >> 4) * 4;
    const float* bp = bias + (size_t)e * N;

    if (OUT_MODE == 0) {
        unsigned short* Y = (unsigned short*)Cout + (size_t)e * M * N;
#pragma unroll
        for (int n = 0; n < 4; ++n) {
            const int cg = bn0 + wc * 64 + n * 16 + fr;
            const float bb = bp[cg];
#pragma unroll
            for (int m = 0; m < 8; ++m) {
                const int rg0 = bm0 + wr * 128 + m * 16 + rowq;
#pragma unroll
                for (int j = 0; j < 4; ++j) {
                    float v = acc[m][n][j] + bb;
                    v = fmaxf(v, 0.0f);
                    Y[(size_t)(rg0 + j) * N + cg] = f2bf(v);
                }
            }
        }
    } else {
        float* O = (float*)Cout + (size_t)e * M * N;
#pragma unroll
        for (int n = 0; n < 4; ++n) {
            const int cg = bn0 + wc * 64 + n * 16 + fr;
            const float bb = bp[cg];
#pragma unroll
            for (int m = 0; m < 8; ++m) {
                const int rg0 = bm0 + wr * 128 + m * 16 + rowq;
#pragma unroll
                for (int j = 0; j < 4; ++j) {
                    O[(size_t)(rg0 + j) * N + cg] = acc[m][n][j] + bb;
                }
            }
        }
    }
}

extern "C" void kernel_launch(void* const* d_in, const int* in_sizes, int n_in,
                              void* d_out, int out_size, void* d_ws, size_t ws_size,
                              hipStream_t stream) {
    const float* x     = (const float*)d_in[0]; // (E,T,D)
    const float* fc1_w = (const float*)d_in[1]; // (E,D,H)
    const float* fc1_b = (const float*)d_in[2]; // (E,1,H)
    const float* fc2_w = (const float*)d_in[3]; // (E,H,D)
    const float* fc2_b = (const float*)d_in[4]; // (E,1,D)
    float* out = (float*)d_out;

    const size_t n_x  = (size_t)E_ * T_ * D_;
    const size_t n_w1 = (size_t)E_ * D_ * H_;
    const size_t n_w2 = (size_t)E_ * H_ * D_;
    const size_t n_y1 = (size_t)E_ * T_ * H_;

    const size_t need = (n_x + n_w1 + n_w2 + n_y1) * sizeof(unsigned short);
    if (ws_size < need) return;

    unsigned short* xb  = (unsigned short*)d_ws;
    unsigned short* w1t = xb + n_x;    // (E,H,D)
    unsigned short* w2t = w1t + n_w1;  // (E,D,H)
    unsigned short* y1  = w2t + n_w2;  // (E,T,H)

    cvt_x_kernel<<<2048, 256, 0, stream>>>((const float4*)x, (uint2*)xb, (long)(n_x / 4));
    {
        dim3 g(H_ / 64, D_ / 64, E_);
        transpose_cvt_kernel<<<g, 256, 0, stream>>>(fc1_w, w1t, D_, H_);
    }
    {
        dim3 g(D_ / 64, H_ / 64, E_);
        transpose_cvt_kernel<<<g, 256, 0, stream>>>(fc2_w, w2t, H_, D_);
    }
    // GEMM1: y1 = relu(x @ W1 + b1), bf16 out. M=T, N=H, K=D
    {
        dim3 g(H_ / 256, T_ / 256, E_);
        gemm256_kernel<D_, 0><<<g, 512, 0, stream>>>(xb, w1t, fc1_b, (void*)y1, T_, H_);
    }
    // GEMM2: out = y1 @ W2 + b2, f32 out. M=T, N=D, K=H
    {
        dim3 g(D_ / 256, T_ / 256, E_);
        gemm256_kernel<H_, 1><<<g, 512, 0, stream>>>(y1, w2t, fc2_b, (void*)out, T_, D_);
    }
}